// Round 1
// baseline (12505.927 us; speedup 1.0000x reference)
//
#include <hip/hip_runtime.h>
#include <hip/hip_bf16.h>

// ---------------------------------------------------------------------------
// GraphS4mer forward: 2-layer GRU (T=2048) -> window means -> per-graph
// (KNN + attention graph, prune, Laplacian reg, SAGE, classifier).
//
// Shapes: x (304, 2048, 32) fp32; H=128; batch=16, N=19, num_dyn=8, Bp=128.
// Output: d_out = [logits(16), reg(1)] fp32 (17 floats).
//
// Workspace: h0 (layer-0 hidden seq) as bf16: 304*2048*128*2 = 159.4 MB,
//            xg fp32: 128*19*128*4 = 1.25 MB.  (requires ws_size >= ~161MB)
// ---------------------------------------------------------------------------

#define NSEQ   304
#define TT     2048
#define HH     128
#define G3     384
#define NNODE  19
#define NBATCH 16
#define NDYN   8
#define NGRAPH 128

static __device__ __forceinline__ float bf16lo(unsigned u){ return __uint_as_float(u << 16); }
static __device__ __forceinline__ float bf16hi(unsigned u){ return __uint_as_float(u & 0xffff0000u); }

// ---------------------------------------------------------------------------
// Fused GRU layer. One block per sequence. 768 threads:
//   j = tid % 384 (gate row), p = tid / 384 (half of the K range).
// Weights held in registers; h in LDS; x staged in 8KB LDS chunks with
// register prefetch (uint4 per thread, 512 threads).
// L0 (DIN=32): thread does gi over 16 dims + gh over 64 dims.
// L1 (DIN=128): p=0 thread does full gi (from x=h0), p=1 full gh.
// Gate threads (tid<128) combine partials, apply sigmoid/tanh, update h.
// L0 writes h0[t] as bf16; L1 accumulates 256-step window means into xg.
// ---------------------------------------------------------------------------
template<bool IS_L1, int DIN, int CH>
__global__ __launch_bounds__(768) void gru_kernel(
    const void* __restrict__ xin,
    const float* __restrict__ Wih, const float* __restrict__ Whh,
    const float* __restrict__ bih, const float* __restrict__ bhh,
    __hip_bfloat16* __restrict__ h0out, float* __restrict__ xgout)
{
  constexpr int NCHUNK = TT / CH;
  __shared__ float sX[CH * DIN];
  __shared__ float sH[HH];
  __shared__ float sGi[2][G3];
  __shared__ float sGh[2][G3];

  const int tid = threadIdx.x;
  const int s   = blockIdx.x;
  const int p   = (tid >= G3) ? 1 : 0;
  const int j   = tid - p * G3;

  // ---- weights into registers (fully unrolled -> register arrays) ----
  float wx[(DIN == 32) ? 16 : 128];
  float wh[(DIN == 32) ? 64 : 1];
  if constexpr (DIN == 32) {
    #pragma unroll
    for (int d = 0; d < 16; ++d) wx[d] = Wih[j * 32 + p * 16 + d];
    #pragma unroll
    for (int k = 0; k < 64; ++k) wh[k] = Whh[j * 128 + p * 64 + k];
  } else {
    const float* Wsel = p ? Whh : Wih;
    #pragma unroll
    for (int k = 0; k < 128; ++k) wx[k] = Wsel[j * 128 + k];
  }

  // ---- biases for gate threads ----
  float b_ir = 0.f, b_iz = 0.f, b_in = 0.f, b_hr = 0.f, b_hz = 0.f, b_hn = 0.f;
  if (tid < HH) {
    b_ir = bih[tid];        b_hr = bhh[tid];
    b_iz = bih[128 + tid];  b_hz = bhh[128 + tid];
    b_in = bih[256 + tid];  b_hn = bhh[256 + tid];
  }
  if (tid < HH) sH[tid] = 0.f;

  const char* src = (const char*)xin +
      (size_t)s * (IS_L1 ? (size_t)TT * 128 * 2 : (size_t)TT * 32 * 4);

  uint4 pf = {0, 0, 0, 0};
  if (tid < 512) pf = *(const uint4*)(src + (size_t)tid * 16);

  float hsum = 0.f;

  for (int c = 0; c < NCHUNK; ++c) {
    __syncthreads();
    if (tid < 512) {
      if constexpr (!IS_L1) {
        float4 f4 = make_float4(__uint_as_float(pf.x), __uint_as_float(pf.y),
                                __uint_as_float(pf.z), __uint_as_float(pf.w));
        *(float4*)&sX[tid * 4] = f4;
      } else {
        const int base = tid * 8;
        sX[base + 0] = bf16lo(pf.x); sX[base + 1] = bf16hi(pf.x);
        sX[base + 2] = bf16lo(pf.y); sX[base + 3] = bf16hi(pf.y);
        sX[base + 4] = bf16lo(pf.z); sX[base + 5] = bf16hi(pf.z);
        sX[base + 6] = bf16lo(pf.w); sX[base + 7] = bf16hi(pf.w);
      }
      if (c + 1 < NCHUNK)
        pf = *(const uint4*)(src + (size_t)(c + 1) * 8192 + (size_t)tid * 16);
    }
    __syncthreads();

    for (int tl = 0; tl < CH; ++tl) {
      const int t = c * CH + tl;
      float gi = 0.f, gh = 0.f;
      if constexpr (DIN == 32) {
        const float* xv = &sX[tl * 32 + p * 16];
        float a0 = 0.f, a1 = 0.f, a2 = 0.f, a3 = 0.f;
        #pragma unroll
        for (int d = 0; d < 16; d += 4) {
          a0 += wx[d] * xv[d];     a1 += wx[d + 1] * xv[d + 1];
          a2 += wx[d + 2] * xv[d + 2]; a3 += wx[d + 3] * xv[d + 3];
        }
        gi = (a0 + a1) + (a2 + a3);
        const float* hv = &sH[p * 64];
        float c0 = 0.f, c1 = 0.f, c2 = 0.f, c3 = 0.f;
        #pragma unroll
        for (int k = 0; k < 64; k += 4) {
          c0 += wh[k] * hv[k];         c1 += wh[k + 1] * hv[k + 1];
          c2 += wh[k + 2] * hv[k + 2]; c3 += wh[k + 3] * hv[k + 3];
        }
        gh = (c0 + c1) + (c2 + c3);
      } else {
        const float* v = p ? sH : &sX[tl * 128];
        float c0 = 0.f, c1 = 0.f, c2 = 0.f, c3 = 0.f;
        #pragma unroll
        for (int k = 0; k < 128; k += 4) {
          c0 += wx[k] * v[k];         c1 += wx[k + 1] * v[k + 1];
          c2 += wx[k + 2] * v[k + 2]; c3 += wx[k + 3] * v[k + 3];
        }
        const float dsum = (c0 + c1) + (c2 + c3);
        if (p) gh = dsum; else gi = dsum;
      }
      sGi[p][j] = gi;
      sGh[p][j] = gh;
      __syncthreads();
      if (tid < HH) {
        const int i = tid;
        const float gir = sGi[0][i] + sGi[1][i] + b_ir;
        const float ghr = sGh[0][i] + sGh[1][i] + b_hr;
        const float giz = sGi[0][128 + i] + sGi[1][128 + i] + b_iz;
        const float ghz = sGh[0][128 + i] + sGh[1][128 + i] + b_hz;
        const float gin = sGi[0][256 + i] + sGi[1][256 + i] + b_in;
        const float ghn = sGh[0][256 + i] + sGh[1][256 + i] + b_hn;
        const float r = 1.f / (1.f + expf(-(gir + ghr)));
        const float z = 1.f / (1.f + expf(-(giz + ghz)));
        const float n = tanhf(gin + r * ghn);
        const float hn = (1.f - z) * n + z * sH[i];
        sH[i] = hn;
        if constexpr (!IS_L1) {
          h0out[((size_t)s * TT + t) * HH + i] = __float2bfloat16(hn);
        } else {
          hsum += hn;
          if ((t & 255) == 255) {
            const int b = s / NNODE;
            const int node = s - b * NNODE;
            const int w = t >> 8;
            xgout[((size_t)(b * NDYN + w) * NNODE + node) * HH + i] =
                hsum * (1.f / 256.f);
            hsum = 0.f;
          }
        }
      }
      __syncthreads();
    }
  }
}

// ---------------------------------------------------------------------------
// Per-graph stage: one block (256 threads) per graph bp in [0,128).
// ---------------------------------------------------------------------------
static __device__ __forceinline__ float blockReduce256(float v, float* sRed)
{
  const int tid = threadIdx.x;
  __syncthreads();              // guard earlier users of sRed
  sRed[tid] = v;
  __syncthreads();
  #pragma unroll
  for (int st = 128; st >= 1; st >>= 1) {
    if (tid < st) sRed[tid] += sRed[tid + st];
    __syncthreads();
  }
  return sRed[0];
}

__global__ __launch_bounds__(256) void graph_kernel(
    const float* __restrict__ xg,
    const float* __restrict__ Wq, const float* __restrict__ Wk,
    const float* __restrict__ Wl, const float* __restrict__ Wr,
    const float* __restrict__ bs, const float* __restrict__ Wc,
    float* __restrict__ out)
{
  const int tid = threadIdx.x;
  const int bp = blockIdx.x;

  __shared__ float sX[NNODE * HH];
  __shared__ float sQ[NNODE * HH];
  __shared__ float sK[NNODE * HH];
  __shared__ float sG[NNODE * NNODE];   // gram <x_n, x_m>
  __shared__ float sA[NNODE * NNODE];   // adj workspace
  __shared__ float sS[NNODE * NNODE];   // attention
  __shared__ float sNorm[NNODE];
  __shared__ float sDis[NNODE];
  __shared__ float sDeg[NNODE];
  __shared__ float sThr;
  __shared__ float sRed[256];

  // load xg for this graph
  for (int idx = tid; idx < NNODE * HH; idx += 256)
    sX[idx] = xg[(size_t)bp * NNODE * HH + idx];
  __syncthreads();

  // row norms
  if (tid < NNODE) {
    float acc = 0.f;
    const float* xv = &sX[tid * HH];
    #pragma unroll 4
    for (int d = 0; d < HH; ++d) acc += xv[d] * xv[d];
    sNorm[tid] = 1.f / sqrtf(acc);
  }
  // gram matrix (all 361 entries)
  for (int e = tid; e < NNODE * NNODE; e += 256) {
    const int n = e / NNODE, m = e % NNODE;
    float acc = 0.f;
    const float* a = &sX[n * HH];
    const float* b = &sX[m * HH];
    #pragma unroll 4
    for (int d = 0; d < HH; ++d) acc += a[d] * b[d];
    sG[e] = acc;
  }
  for (int e = tid; e < NNODE * NNODE; e += 256) sA[e] = 0.f;
  __syncthreads();

  // top-3 cosine KNN per row (strict > keeps earliest index, matching top_k)
  if (tid < NNODE) {
    const int r = tid;
    const float nr = sNorm[r];
    float v0 = -1e30f, v1 = -1e30f, v2 = -1e30f;
    int i0 = 0, i1 = 0, i2 = 0;
    for (int m = 0; m < NNODE; ++m) {
      const float v = sG[r * NNODE + m] * nr * sNorm[m];
      if (v > v0)      { v2 = v1; i2 = i1; v1 = v0; i1 = i0; v0 = v; i0 = m; }
      else if (v > v1) { v2 = v1; i2 = i1; v1 = v;  i1 = m; }
      else if (v > v2) { v2 = v;  i2 = m; }
    }
    sA[r * NNODE + i0] = fmaxf(v0, 0.f);
    sA[r * NNODE + i1] = fmaxf(v1, 0.f);
    sA[r * NNODE + i2] = fmaxf(v2, 0.f);
  }
  __syncthreads();

  // symmetrize + force diag=1 (register staging to avoid RAW hazard)
  {
    float t0 = 0.f, t1 = 0.f;
    if (tid < 361) {
      const int n = tid / NNODE, m = tid % NNODE;
      t0 = (n == m) ? 1.f : 0.5f * (sA[n * NNODE + m] + sA[m * NNODE + n]);
    }
    if (tid + 256 < 361) {
      const int e = tid + 256;
      const int n = e / NNODE, m = e % NNODE;
      t1 = (n == m) ? 1.f : 0.5f * (sA[n * NNODE + m] + sA[m * NNODE + n]);
    }
    __syncthreads();
    if (tid < 361) sA[tid] = t0;
    if (tid + 256 < 361) sA[tid + 256] = t1;
  }

  // q, k projections
  for (int o = tid; o < NNODE * HH; o += 256) {
    const int n = o >> 7, hh = o & 127;
    float aq = 0.f, ak = 0.f;
    const float* xv = &sX[n * HH];
    const float* wq = &Wq[hh * HH];
    const float* wk = &Wk[hh * HH];
    #pragma unroll 4
    for (int d = 0; d < HH; ++d) { const float xx = xv[d]; aq += xx * wq[d]; ak += xx * wk[d]; }
    sQ[o] = aq; sK[o] = ak;
  }
  __syncthreads();

  // attention logits
  for (int e = tid; e < NNODE * NNODE; e += 256) {
    const int n = e / NNODE, m = e % NNODE;
    float acc = 0.f;
    const float* a = &sQ[n * HH];
    const float* b = &sK[m * HH];
    #pragma unroll 4
    for (int d = 0; d < HH; ++d) acc += a[d] * b[d];
    sS[e] = acc * 0.08838834764831845f;   // 1/sqrt(128)
  }
  __syncthreads();
  // softmax per row
  if (tid < NNODE) {
    const int r = tid;
    float mx = -1e30f;
    for (int m = 0; m < NNODE; ++m) mx = fmaxf(mx, sS[r * NNODE + m]);
    float sum = 0.f;
    for (int m = 0; m < NNODE; ++m) sum += expf(sS[r * NNODE + m] - mx);
    const float inv = 1.f / sum;
    for (int m = 0; m < NNODE; ++m)
      sS[r * NNODE + m] = expf(sS[r * NNODE + m] - mx) * inv;
  }
  __syncthreads();

  // adj = 0.1*adj_knn + 0.9*sym(attn)   (each thread touches only own sA[e])
  for (int e = tid; e < NNODE * NNODE; e += 256) {
    const int n = e / NNODE, m = e % NNODE;
    sA[e] = 0.1f * sA[e] + 0.45f * (sS[n * NNODE + m] + sS[m * NNODE + n]);
  }
  __syncthreads();

  // prune threshold: value at descending-sorted index 180 of the 361 entries
  for (int e = tid; e < NNODE * NNODE; e += 256) {
    const float v = sA[e];
    int cg = 0, ce = 0;
    for (int f = 0; f < NNODE * NNODE; ++f) {
      const float u = sA[f];
      cg += (u > v);
      ce += (u == v);
    }
    if (cg <= 180 && cg + ce > 180) sThr = v;
  }
  __syncthreads();
  {
    const float thr = sThr;
    for (int e = tid; e < NNODE * NNODE; e += 256)
      sA[e] = (sA[e] > thr) ? sA[e] : 0.f;
  }
  __syncthreads();

  // degrees: dis for Laplacian, deg for SAGE mean
  if (tid < NNODE) {
    const int r = tid;
    float dsum = 0.f;
    int cnt = 0;
    for (int m = 0; m < NNODE; ++m) {
      const float v = sA[r * NNODE + m];
      dsum += v;
      if (m != r && v > 0.f) ++cnt;
    }
    sDis[r] = (dsum > 0.f) ? 1.f / sqrtf(dsum) : 0.f;
    sDeg[r] = (float)(cnt < 1 ? 1 : cnt);
  }
  __syncthreads();

  // reg: trace(X^T L X) = sum_{n,m} L[n,m]*G[n,m]
  float regp = 0.f;
  for (int e = tid; e < NNODE * NNODE; e += 256) {
    const int n = e / NNODE, m = e % NNODE;
    const float Lnm = ((n == m) ? 1.f : 0.f) - sDis[n] * sDis[m] * sA[e];
    regp += Lnm * sG[e];
  }
  {
    const float tr = blockReduce256(regp, sRed);
    if (tid == 0)
      atomicAdd(out + 16, tr * (1.f / (16384.f * (float)NGRAPH)));
  }
  __syncthreads();

  // SAGE mean aggregation into sQ (reused)
  for (int o = tid; o < NNODE * HH; o += 256) {
    const int n = o >> 7, d = o & 127;
    float acc = 0.f;
    for (int m = 0; m < NNODE; ++m)
      if (m != n && sA[n * NNODE + m] > 0.f) acc += sX[m * HH + d];
    sQ[o] = acc / sDeg[n];
  }
  __syncthreads();

  // out = relu(agg@Wl^T + b + x@Wr^T); fold directly into classifier
  float lgp = 0.f;
  for (int o = tid; o < NNODE * HH; o += 256) {
    const int n = o >> 7, hh = o & 127;
    float acc = bs[hh];
    const float* av = &sQ[n * HH];
    const float* xv = &sX[n * HH];
    const float* wl = &Wl[hh * HH];
    const float* wr = &Wr[hh * HH];
    #pragma unroll 4
    for (int d = 0; d < HH; ++d) acc += av[d] * wl[d] + xv[d] * wr[d];
    lgp += fmaxf(acc, 0.f) * Wc[hh];
  }
  {
    const float tot = blockReduce256(lgp, sRed);
    if (tid == 0)
      atomicAdd(out + (bp >> 3), tot * 0.125f);   // mean over 8 dyn windows
  }
}

__global__ void init_out_kernel(float* __restrict__ out, const float* __restrict__ bc)
{
  const int i = threadIdx.x;
  if (i < 16) out[i] = bc[0];
  else if (i == 16) out[16] = 0.f;
}

// ---------------------------------------------------------------------------
extern "C" void kernel_launch(void* const* d_in, const int* in_sizes, int n_in,
                              void* d_out, int out_size, void* d_ws, size_t ws_size,
                              hipStream_t stream)
{
  const float* x    = (const float*)d_in[0];
  const float* Wih0 = (const float*)d_in[1];
  const float* Whh0 = (const float*)d_in[2];
  const float* bih0 = (const float*)d_in[3];
  const float* bhh0 = (const float*)d_in[4];
  const float* Wih1 = (const float*)d_in[5];
  const float* Whh1 = (const float*)d_in[6];
  const float* bih1 = (const float*)d_in[7];
  const float* bhh1 = (const float*)d_in[8];
  const float* Wq   = (const float*)d_in[9];
  const float* Wk   = (const float*)d_in[10];
  const float* Wl   = (const float*)d_in[11];
  const float* Wr   = (const float*)d_in[12];
  const float* bsg  = (const float*)d_in[13];
  const float* Wc   = (const float*)d_in[14];
  const float* bc   = (const float*)d_in[15];
  float* out = (float*)d_out;

  const size_t H0_BYTES = (size_t)NSEQ * TT * HH * 2;   // 159.4 MB bf16
  __hip_bfloat16* h0 = (__hip_bfloat16*)d_ws;
  float* xg = (float*)((char*)d_ws + H0_BYTES);         // +1.25 MB fp32

  init_out_kernel<<<1, 64, 0, stream>>>(out, bc);
  gru_kernel<false, 32, 64><<<NSEQ, 768, 0, stream>>>(
      (const void*)x, Wih0, Whh0, bih0, bhh0, h0, nullptr);
  gru_kernel<true, 128, 32><<<NSEQ, 768, 0, stream>>>(
      (const void*)h0, Wih1, Whh1, bih1, bhh1, nullptr, xg);
  graph_kernel<<<NGRAPH, 256, 0, stream>>>(xg, Wq, Wk, Wl, Wr, bsg, Wc, out);
}

// Round 2
// 3363.065 us; speedup vs baseline: 3.7186x; 3.7186x over previous
//
#include <hip/hip_runtime.h>
#include <hip/hip_bf16.h>

// ---------------------------------------------------------------------------
// GraphS4mer forward, MFMA-batched GRU.
//   gru2_kernel: 19 blocks x 512 threads (8 waves). Each block owns 16
//   sequences; both GRU layers advance step-synchronized. Per step/wave:
//   39 v_mfma_f32_16x16x32_bf16 (L0 gi 3 + L0 rec 12 + L1 gi 12 + L1 rec 12).
//   Weights live in VGPRs as B-fragments; h0/h1 live in LDS (A-frag layout,
//   pitch 136 bf16 -> 2-way-max bank aliasing, free). Gate tiles are mapped
//   so wave w holds r/z/n pre-activations for hidden units j=16w+(lane&15):
//   the gate nonlinearity is wave-local; h_prev stays in fp32 registers.
//   Window means accumulate in registers -> xg (only ws usage, 1.25 MB).
// ---------------------------------------------------------------------------

#define NSEQ   304
#define TT     2048
#define HH     128
#define NNODE  19
#define NBATCH 16
#define NDYN   8
#define NGRAPH 128
#define PITCH  136            // bf16 pitch: stride 272B -> banks 4m%32, 2-way max

typedef __bf16 bf16x8 __attribute__((ext_vector_type(8)));
typedef float  f32x4  __attribute__((ext_vector_type(4)));

static __device__ __forceinline__ f32x4 mfma16(bf16x8 a, bf16x8 b, f32x4 c) {
  return __builtin_amdgcn_mfma_f32_16x16x32_bf16(a, b, c, 0, 0, 0);
}
static __device__ __forceinline__ float fast_sigmoid(float x) {
  const float e = __builtin_amdgcn_exp2f(-1.4426950408889634f * x);
  return __builtin_amdgcn_rcpf(1.f + e);
}
static __device__ __forceinline__ float fast_tanh(float x) {
  const float e = __builtin_amdgcn_exp2f(2.8853900817779268f * x);
  return 1.f - 2.f * __builtin_amdgcn_rcpf(1.f + e);
}

__global__ __launch_bounds__(512, 2) void gru2_kernel(
    const float* __restrict__ x,
    const float* __restrict__ Wih0, const float* __restrict__ Whh0,
    const float* __restrict__ bih0, const float* __restrict__ bhh0,
    const float* __restrict__ Wih1, const float* __restrict__ Whh1,
    const float* __restrict__ bih1, const float* __restrict__ bhh1,
    float* __restrict__ xg)
{
  __shared__ __align__(16) __bf16 sH0[16 * PITCH];
  __shared__ __align__(16) __bf16 sH1[16 * PITCH];

  const int tid = threadIdx.x;
  const int w   = tid >> 6;          // wave 0..7
  const int l   = tid & 63;
  const int lm  = l & 15;            // A row (seq) / B col (gate-in-tile)
  const int lq  = l >> 4;            // quad
  const int g   = blockIdx.x;
  const int j   = 16 * w + lm;       // hidden unit this lane's gates belong to

  // ---- B-fragment preload: wave w covers gate tiles {w, 8+w, 16+w} ----
  // gsel 0/1/2 -> r/z/n gate rows 128*gsel + j; lane holds 8 consecutive k.
  bf16x8 bI0[3], bH0[3][4], bI1[3][4], bH1[3][4];
  #pragma unroll
  for (int gsel = 0; gsel < 3; ++gsel) {
    const int row = 128 * gsel + j;
    {
      const float* p = Wih0 + row * 32 + lq * 8;
      bf16x8 f;
      #pragma unroll
      for (int u = 0; u < 8; ++u) f[u] = (__bf16)p[u];
      bI0[gsel] = f;
    }
    #pragma unroll
    for (int kc = 0; kc < 4; ++kc) {
      const float* p0 = Whh0 + row * 128 + kc * 32 + lq * 8;
      const float* p1 = Wih1 + row * 128 + kc * 32 + lq * 8;
      const float* p2 = Whh1 + row * 128 + kc * 32 + lq * 8;
      bf16x8 f0, f1, f2;
      #pragma unroll
      for (int u = 0; u < 8; ++u) {
        f0[u] = (__bf16)p0[u]; f1[u] = (__bf16)p1[u]; f2[u] = (__bf16)p2[u];
      }
      bH0[gsel][kc] = f0; bI1[gsel][kc] = f1; bH1[gsel][kc] = f2;
    }
  }

  // biases (fold bih+bhh for r,z; keep n-gate halves separate)
  const float Br0  = bih0[j] + bhh0[j];
  const float Bz0  = bih0[128 + j] + bhh0[128 + j];
  const float bin0 = bih0[256 + j];
  const float bhn0 = bhh0[256 + j];
  const float Br1  = bih1[j] + bhh1[j];
  const float Bz1  = bih1[128 + j] + bhh1[128 + j];
  const float bin1 = bih1[256 + j];
  const float bhn1 = bhh1[256 + j];

  // x row for this lane's A0 fragment: seq g*16+lm, k = lq*8..lq*8+7
  const float* xrow = x + ((size_t)(g * 16 + lm) * TT) * 32 + lq * 8;
  float4 pfa = *(const float4*)(xrow);
  float4 pfb = *(const float4*)(xrow + 4);

  float h0p[4] = {0.f, 0.f, 0.f, 0.f};
  float h1p[4] = {0.f, 0.f, 0.f, 0.f};
  float hsum[4] = {0.f, 0.f, 0.f, 0.f};

  for (int i = tid; i < 16 * PITCH; i += 512) {
    sH0[i] = (__bf16)0.f; sH1[i] = (__bf16)0.f;
  }
  __syncthreads();

  const int aoff = lm * PITCH + lq * 8;   // A-frag base (elements)
  const f32x4 z4 = {0.f, 0.f, 0.f, 0.f};

  for (int t = 0; t < TT; ++t) {
    // ---- A0 fragment from prefetched x, issue next prefetch ----
    bf16x8 a0;
    a0[0] = (__bf16)pfa.x; a0[1] = (__bf16)pfa.y;
    a0[2] = (__bf16)pfa.z; a0[3] = (__bf16)pfa.w;
    a0[4] = (__bf16)pfb.x; a0[5] = (__bf16)pfb.y;
    a0[6] = (__bf16)pfb.z; a0[7] = (__bf16)pfb.w;
    {
      const int tn = (t + 1 < TT) ? t + 1 : t;
      pfa = *(const float4*)(xrow + (size_t)tn * 32);
      pfb = *(const float4*)(xrow + (size_t)tn * 32 + 4);
    }

    // ---- L0: gi (K=32 from x) + recurrent (K=128 from h0_{t-1}) ----
    bf16x8 ah0[4];
    #pragma unroll
    for (int kc = 0; kc < 4; ++kc)
      ah0[kc] = *(const bf16x8*)&sH0[aoff + kc * 32];

    f32x4 Cr = mfma16(a0, bI0[0], z4);
    f32x4 Cz = mfma16(a0, bI0[1], z4);
    f32x4 Cn = mfma16(a0, bI0[2], z4);
    f32x4 Cm = z4;
    #pragma unroll
    for (int kc = 0; kc < 4; ++kc) {
      Cr = mfma16(ah0[kc], bH0[0][kc], Cr);
      Cz = mfma16(ah0[kc], bH0[1][kc], Cz);
      Cm = mfma16(ah0[kc], bH0[2][kc], Cm);
    }
    __bf16 hnb[4];
    #pragma unroll
    for (int q = 0; q < 4; ++q) {
      const float r  = fast_sigmoid(Cr[q] + Br0);
      const float zz = fast_sigmoid(Cz[q] + Bz0);
      const float n  = fast_tanh(Cn[q] + bin0 + r * (Cm[q] + bhn0));
      const float h  = n + zz * (h0p[q] - n);
      h0p[q] = h;
      hnb[q] = (__bf16)h;
    }
    __syncthreads();   // (1) all waves' sH0 (and prior sH1) reads complete

    #pragma unroll
    for (int q = 0; q < 4; ++q)
      sH0[(lq * 4 + q) * PITCH + j] = hnb[q];
    // read h1_{t-1} frags here: before (2), so later sH1 writes can't race
    bf16x8 ah1[4];
    #pragma unroll
    for (int kc = 0; kc < 4; ++kc)
      ah1[kc] = *(const bf16x8*)&sH1[aoff + kc * 32];
    __syncthreads();   // (2) h0_t visible to all waves

    // ---- L1: gi (K=128 from h0_t) + recurrent (K=128 from h1_{t-1}) ----
    bf16x8 ag[4];
    #pragma unroll
    for (int kc = 0; kc < 4; ++kc)
      ag[kc] = *(const bf16x8*)&sH0[aoff + kc * 32];

    f32x4 Dr = z4, Dz = z4, Dn = z4, Dm = z4;
    #pragma unroll
    for (int kc = 0; kc < 4; ++kc) {
      Dr = mfma16(ag[kc], bI1[0][kc], Dr);
      Dz = mfma16(ag[kc], bI1[1][kc], Dz);
      Dn = mfma16(ag[kc], bI1[2][kc], Dn);
    }
    #pragma unroll
    for (int kc = 0; kc < 4; ++kc) {
      Dr = mfma16(ah1[kc], bH1[0][kc], Dr);
      Dz = mfma16(ah1[kc], bH1[1][kc], Dz);
      Dm = mfma16(ah1[kc], bH1[2][kc], Dm);
    }
    #pragma unroll
    for (int q = 0; q < 4; ++q) {
      const float r  = fast_sigmoid(Dr[q] + Br1);
      const float zz = fast_sigmoid(Dz[q] + Bz1);
      const float n  = fast_tanh(Dn[q] + bin1 + r * (Dm[q] + bhn1));
      const float h  = n + zz * (h1p[q] - n);
      h1p[q] = h;
      hsum[q] += h;
      sH1[(lq * 4 + q) * PITCH + j] = (__bf16)h;
    }
    if ((t & 255) == 255) {
      const int win = t >> 8;
      #pragma unroll
      for (int q = 0; q < 4; ++q) {
        const int seq  = g * 16 + lq * 4 + q;
        const int b    = seq / NNODE;
        const int node = seq - b * NNODE;
        xg[((size_t)(b * NDYN + win) * NNODE + node) * HH + j] =
            hsum[q] * (1.f / 256.f);
        hsum[q] = 0.f;
      }
    }
    __syncthreads();   // (3) sH1 writes visible before next iter's reads
  }
}

// ---------------------------------------------------------------------------
// Per-graph stage (unchanged from R1 — negligible time, verified correct).
// ---------------------------------------------------------------------------
static __device__ __forceinline__ float blockReduce256(float v, float* sRed)
{
  const int tid = threadIdx.x;
  __syncthreads();
  sRed[tid] = v;
  __syncthreads();
  #pragma unroll
  for (int st = 128; st >= 1; st >>= 1) {
    if (tid < st) sRed[tid] += sRed[tid + st];
    __syncthreads();
  }
  return sRed[0];
}

__global__ __launch_bounds__(256) void graph_kernel(
    const float* __restrict__ xg,
    const float* __restrict__ Wq, const float* __restrict__ Wk,
    const float* __restrict__ Wl, const float* __restrict__ Wr,
    const float* __restrict__ bs, const float* __restrict__ Wc,
    float* __restrict__ out)
{
  const int tid = threadIdx.x;
  const int bp = blockIdx.x;

  __shared__ float sX[NNODE * HH];
  __shared__ float sQ[NNODE * HH];
  __shared__ float sK[NNODE * HH];
  __shared__ float sG[NNODE * NNODE];
  __shared__ float sA[NNODE * NNODE];
  __shared__ float sS[NNODE * NNODE];
  __shared__ float sNorm[NNODE];
  __shared__ float sDis[NNODE];
  __shared__ float sDeg[NNODE];
  __shared__ float sThr;
  __shared__ float sRed[256];

  for (int idx = tid; idx < NNODE * HH; idx += 256)
    sX[idx] = xg[(size_t)bp * NNODE * HH + idx];
  __syncthreads();

  if (tid < NNODE) {
    float acc = 0.f;
    const float* xv = &sX[tid * HH];
    #pragma unroll 4
    for (int d = 0; d < HH; ++d) acc += xv[d] * xv[d];
    sNorm[tid] = 1.f / sqrtf(acc);
  }
  for (int e = tid; e < NNODE * NNODE; e += 256) {
    const int n = e / NNODE, m = e % NNODE;
    float acc = 0.f;
    const float* a = &sX[n * HH];
    const float* b = &sX[m * HH];
    #pragma unroll 4
    for (int d = 0; d < HH; ++d) acc += a[d] * b[d];
    sG[e] = acc;
  }
  for (int e = tid; e < NNODE * NNODE; e += 256) sA[e] = 0.f;
  __syncthreads();

  if (tid < NNODE) {
    const int r = tid;
    const float nr = sNorm[r];
    float v0 = -1e30f, v1 = -1e30f, v2 = -1e30f;
    int i0 = 0, i1 = 0, i2 = 0;
    for (int m = 0; m < NNODE; ++m) {
      const float v = sG[r * NNODE + m] * nr * sNorm[m];
      if (v > v0)      { v2 = v1; i2 = i1; v1 = v0; i1 = i0; v0 = v; i0 = m; }
      else if (v > v1) { v2 = v1; i2 = i1; v1 = v;  i1 = m; }
      else if (v > v2) { v2 = v;  i2 = m; }
    }
    sA[r * NNODE + i0] = fmaxf(v0, 0.f);
    sA[r * NNODE + i1] = fmaxf(v1, 0.f);
    sA[r * NNODE + i2] = fmaxf(v2, 0.f);
  }
  __syncthreads();

  {
    float t0 = 0.f, t1 = 0.f;
    if (tid < 361) {
      const int n = tid / NNODE, m = tid % NNODE;
      t0 = (n == m) ? 1.f : 0.5f * (sA[n * NNODE + m] + sA[m * NNODE + n]);
    }
    if (tid + 256 < 361) {
      const int e = tid + 256;
      const int n = e / NNODE, m = e % NNODE;
      t1 = (n == m) ? 1.f : 0.5f * (sA[n * NNODE + m] + sA[m * NNODE + n]);
    }
    __syncthreads();
    if (tid < 361) sA[tid] = t0;
    if (tid + 256 < 361) sA[tid + 256] = t1;
  }

  for (int o = tid; o < NNODE * HH; o += 256) {
    const int n = o >> 7, hh = o & 127;
    float aq = 0.f, ak = 0.f;
    const float* xv = &sX[n * HH];
    const float* wq = &Wq[hh * HH];
    const float* wk = &Wk[hh * HH];
    #pragma unroll 4
    for (int d = 0; d < HH; ++d) { const float xx = xv[d]; aq += xx * wq[d]; ak += xx * wk[d]; }
    sQ[o] = aq; sK[o] = ak;
  }
  __syncthreads();

  for (int e = tid; e < NNODE * NNODE; e += 256) {
    const int n = e / NNODE, m = e % NNODE;
    float acc = 0.f;
    const float* a = &sQ[n * HH];
    const float* b = &sK[m * HH];
    #pragma unroll 4
    for (int d = 0; d < HH; ++d) acc += a[d] * b[d];
    sS[e] = acc * 0.08838834764831845f;
  }
  __syncthreads();
  if (tid < NNODE) {
    const int r = tid;
    float mx = -1e30f;
    for (int m = 0; m < NNODE; ++m) mx = fmaxf(mx, sS[r * NNODE + m]);
    float sum = 0.f;
    for (int m = 0; m < NNODE; ++m) sum += expf(sS[r * NNODE + m] - mx);
    const float inv = 1.f / sum;
    for (int m = 0; m < NNODE; ++m)
      sS[r * NNODE + m] = expf(sS[r * NNODE + m] - mx) * inv;
  }
  __syncthreads();

  for (int e = tid; e < NNODE * NNODE; e += 256) {
    const int n = e / NNODE, m = e % NNODE;
    sA[e] = 0.1f * sA[e] + 0.45f * (sS[n * NNODE + m] + sS[m * NNODE + n]);
  }
  __syncthreads();

  for (int e = tid; e < NNODE * NNODE; e += 256) {
    const float v = sA[e];
    int cg = 0, ce = 0;
    for (int f = 0; f < NNODE * NNODE; ++f) {
      const float u = sA[f];
      cg += (u > v);
      ce += (u == v);
    }
    if (cg <= 180 && cg + ce > 180) sThr = v;
  }
  __syncthreads();
  {
    const float thr = sThr;
    for (int e = tid; e < NNODE * NNODE; e += 256)
      sA[e] = (sA[e] > thr) ? sA[e] : 0.f;
  }
  __syncthreads();

  if (tid < NNODE) {
    const int r = tid;
    float dsum = 0.f;
    int cnt = 0;
    for (int m = 0; m < NNODE; ++m) {
      const float v = sA[r * NNODE + m];
      dsum += v;
      if (m != r && v > 0.f) ++cnt;
    }
    sDis[r] = (dsum > 0.f) ? 1.f / sqrtf(dsum) : 0.f;
    sDeg[r] = (float)(cnt < 1 ? 1 : cnt);
  }
  __syncthreads();

  float regp = 0.f;
  for (int e = tid; e < NNODE * NNODE; e += 256) {
    const int n = e / NNODE, m = e % NNODE;
    const float Lnm = ((n == m) ? 1.f : 0.f) - sDis[n] * sDis[m] * sA[e];
    regp += Lnm * sG[e];
  }
  {
    const float tr = blockReduce256(regp, sRed);
    if (tid == 0)
      atomicAdd(out + 16, tr * (1.f / (16384.f * (float)NGRAPH)));
  }
  __syncthreads();

  for (int o = tid; o < NNODE * HH; o += 256) {
    const int n = o >> 7, d = o & 127;
    float acc = 0.f;
    for (int m = 0; m < NNODE; ++m)
      if (m != n && sA[n * NNODE + m] > 0.f) acc += sX[m * HH + d];
    sQ[o] = acc / sDeg[n];
  }
  __syncthreads();

  float lgp = 0.f;
  for (int o = tid; o < NNODE * HH; o += 256) {
    const int n = o >> 7, hh = o & 127;
    float acc = bs[hh];
    const float* av = &sQ[n * HH];
    const float* xv = &sX[n * HH];
    const float* wl = &Wl[hh * HH];
    const float* wr = &Wr[hh * HH];
    #pragma unroll 4
    for (int d = 0; d < HH; ++d) acc += av[d] * wl[d] + xv[d] * wr[d];
    lgp += fmaxf(acc, 0.f) * Wc[hh];
  }
  {
    const float tot = blockReduce256(lgp, sRed);
    if (tid == 0)
      atomicAdd(out + (bp >> 3), tot * 0.125f);
  }
}

__global__ void init_out_kernel(float* __restrict__ out, const float* __restrict__ bc)
{
  const int i = threadIdx.x;
  if (i < 16) out[i] = bc[0];
  else if (i == 16) out[16] = 0.f;
}

// ---------------------------------------------------------------------------
extern "C" void kernel_launch(void* const* d_in, const int* in_sizes, int n_in,
                              void* d_out, int out_size, void* d_ws, size_t ws_size,
                              hipStream_t stream)
{
  const float* x    = (const float*)d_in[0];
  const float* Wih0 = (const float*)d_in[1];
  const float* Whh0 = (const float*)d_in[2];
  const float* bih0 = (const float*)d_in[3];
  const float* bhh0 = (const float*)d_in[4];
  const float* Wih1 = (const float*)d_in[5];
  const float* Whh1 = (const float*)d_in[6];
  const float* bih1 = (const float*)d_in[7];
  const float* bhh1 = (const float*)d_in[8];
  const float* Wq   = (const float*)d_in[9];
  const float* Wk   = (const float*)d_in[10];
  const float* Wl   = (const float*)d_in[11];
  const float* Wr   = (const float*)d_in[12];
  const float* bsg  = (const float*)d_in[13];
  const float* Wc   = (const float*)d_in[14];
  const float* bc   = (const float*)d_in[15];
  float* out = (float*)d_out;

  float* xg = (float*)d_ws;   // 128*19*128 fp32 = 1.25 MB

  init_out_kernel<<<1, 64, 0, stream>>>(out, bc);
  gru2_kernel<<<NSEQ / NBATCH, 512, 0, stream>>>(
      x, Wih0, Whh0, bih0, bhh0, Wih1, Whh1, bih1, bhh1, xg);
  graph_kernel<<<NGRAPH, 256, 0, stream>>>(xg, Wq, Wk, Wl, Wr, bsg, Wc, out);
}